// Round 2
// 195.480 us; speedup vs baseline: 1.0066x; 1.0066x over previous
//
#include <hip/hip_runtime.h>
#include <hip/hip_bf16.h>
#include <math.h>

#define B_ 2
#define S_ 2048
#define E_ 1024
#define H_ 16
#define D_ 64
#define M_ (B_*S_)

typedef __attribute__((ext_vector_type(8))) short short8v;
typedef __attribute__((ext_vector_type(4))) float floatx4;

__device__ __forceinline__ short f2bf(float f) {
    union { float f; unsigned u; } x; x.f = f;
    unsigned r = (x.u + 0x7fffu + ((x.u >> 16) & 1u)) >> 16;  // RNE
    return (short)r;
}

// pack two fp32 -> two bf16 in one v_perm_b32 (round-half-up)
__device__ __forceinline__ unsigned pk_bf16(float a, float b) {
    union { float f; unsigned u; } x, y;
    x.f = a; y.f = b;
    return __builtin_amdgcn_perm(y.u + 0x8000u, x.u + 0x8000u, 0x07060302u);
}

__device__ __forceinline__ float fast_exp2(float x) {
#if __has_builtin(__builtin_amdgcn_exp2f)
    return __builtin_amdgcn_exp2f(x);
#else
    return __expf(x * 0.6931471805599453f);
#endif
}

// async global->LDS, 16B per lane; LDS dest = wave-uniform base + lane*16
__device__ __forceinline__ void gl2lds16(const void* g, void* l) {
    __builtin_amdgcn_global_load_lds(
        (const __attribute__((address_space(1))) void*)g,
        (__attribute__((address_space(3))) void*)l, 16, 0, 0);
}

// XOR-swizzled fragment offset into a 64-col bf16 LDS tile:
// logical (row, 16B-chunk cg) lives at row*64 + ((cg ^ (row&7))*8).
// Staged by reading global chunk ((l&7)^(l>>3)) per lane (see stage uses).
__device__ __forceinline__ int swz_off(int row, int cg) {
    return row*64 + (((cg ^ (row & 7)) & 7) << 3);
}

// ---------------------------------------------------------------------------
// Pre-pass 1: x fp32 -> bf16 flat copy.
// ---------------------------------------------------------------------------
__global__ __launch_bounds__(256) void convert_x(
    const float* __restrict__ x, short* __restrict__ xb)
{
    const size_t i = ((size_t)blockIdx.x*256 + threadIdx.x) * 8;
    float4 a = *(const float4*)(x + i);
    float4 b = *(const float4*)(x + i + 4);
    int4 p = { (int)pk_bf16(a.x,a.y), (int)pk_bf16(a.z,a.w),
               (int)pk_bf16(b.x,b.y), (int)pk_bf16(b.z,b.w) };
    *(int4*)(xb + i) = p;
}

// ---------------------------------------------------------------------------
// Pre-pass 2: W [k][n] fp32 -> Wt [n][k] bf16 (32x32 LDS tile transpose).
// ---------------------------------------------------------------------------
__global__ __launch_bounds__(256) void transpose_w(
    const float* __restrict__ W0, const float* __restrict__ W1,
    const float* __restrict__ W2, const float* __restrict__ W3,
    short* __restrict__ T0, short* __restrict__ T1,
    short* __restrict__ T2, short* __restrict__ T3)
{
    const int z = blockIdx.z;
    const float* W = (z==0)?W0:(z==1)?W1:(z==2)?W2:W3;
    short*       T = (z==0)?T0:(z==1)?T1:(z==2)?T2:T3;
    __shared__ float tile[32][33];
    const int k0 = blockIdx.y*32, n0 = blockIdx.x*32;
    const int r = threadIdx.x >> 5, c = threadIdx.x & 31;
    #pragma unroll
    for (int i=0;i<4;i++)
        tile[r+8*i][c] = W[(size_t)(k0+r+8*i)*E_ + n0 + c];
    __syncthreads();
    #pragma unroll
    for (int i=0;i<4;i++)
        T[(size_t)(n0+r+8*i)*E_ + k0 + c] = f2bf(tile[c][r+8*i]);
}

// ---------------------------------------------------------------------------
// Fused QKV GEMM — 256x256 tile, BK=64, 8 waves (2Mx4N), 512 threads,
// 8-phase counted-vmcnt schedule (T3+T4) + setprio (T5) + XOR swizzle (T2).
// A = xb bf16 [4096,1024]; B = Wt bf16 [3072][1024] (Tq|Tk|Tv contiguous).
// Grid 192 = 16m x 12n, XCD-chunked swizzle; per-wave output 128x64
// (acc[8][4] 16x16 frags). LDS 128 KiB: 2 dbuf x (A 256x64 + B 256x64) bf16.
//
// Per K-tile (4 phases, 16 MFMA each):
//   ph0: ds_read a[M0-3], b[N0-1]; stage A-half0(t+1) -> buf^1 ; MFMA M0-3xN0-1
//   ph1: ds_read b[N2-3];          stage A-half1(t+1) -> buf^1 ; MFMA M0-3xN2-3
//   ph2: ds_read a[M4-7];          stage B-half0(t+2) -> buf   ; MFMA M4-7xN0-1
//   ph3:                           stage B-half1(t+2) -> buf   ; MFMA M4-7xN2-3
//        then s_waitcnt vmcnt(4) (tile t+1 fully landed; 2 newest half-tiles
//        may stay in flight) + raw s_barrier.  Never vmcnt(0) mid-loop.
// WAR safety: a region is re-staged only in a phase after its last read has
// been confirmed by a barrier (B halves done after ph1, A halves after ph2).
// Barrier count is block-uniform (all stage conditions uniform): no deadlock.
//
// z = nf0>>10 (block-uniform): 0->Q [B,H,S,D] exp2-scaled; 1->K swizzled
// tiles; 2->V swizzled [d][key] tiles (attn-side layouts, unchanged).
// ---------------------------------------------------------------------------
__global__ __launch_bounds__(512, 2) void qkv_gemm(
    const short* __restrict__ xb, const short* __restrict__ Wt,
    const float* __restrict__ bq, const float* __restrict__ bk, const float* __restrict__ bv,
    short* __restrict__ Qo, short* __restrict__ Ko, short* __restrict__ Vo)
{
    __shared__ __align__(16) short As[2][256*64];
    __shared__ __align__(16) short Bs[2][256*64];

    const int t = threadIdx.x;
    const int wave = t >> 6, lane = t & 63;
    const int quad = lane >> 4, l15 = lane & 15;
    const int wr = wave >> 2, wc = wave & 3;          // 2x4 wave grid

    const int bid = blockIdx.x;
    const int sw  = (bid & 7) * 24 + (bid >> 3);      // XCD chunk (192%8==0)
    const int m0  = (sw / 12) * 256;                  // 16 m-tiles
    const int nti = sw % 12;                          // 12 n-tiles
    const int nf0 = nti * 256;
    const int z   = nf0 >> 10;
    const float* bb = (z==0) ? bq : (z==1) ? bk : bv;
    short* out      = (z==0) ? Qo : (z==1) ? Ko : Vo;
    const float sc  = (z==0) ? 0.18033688011112042f : 1.0f;

    const int sr8 = lane >> 3;
    const int scs = ((lane & 7) ^ sr8) * 8;           // pre-swizzled src chunk

    const short* Ag = xb + (size_t)m0  * E_;
    const short* Bg = Wt + (size_t)nf0 * E_;

    floatx4 acc[8][4];
    #pragma unroll
    for (int i=0;i<8;i++)
        #pragma unroll
        for (int j=0;j<4;j++) acc[i][j] = (floatx4){0.f,0.f,0.f,0.f};

    // stage one 128-row half-tile (2 x global_load_lds per thread)
    auto stageA = [&](int p, int h, int kt) {
        const int rb = h*128 + wave*16;
        const short* src = Ag + (size_t)(rb + sr8)*E_ + kt*64 + scs;
        #pragma unroll
        for (int c=0;c<2;c++)
            gl2lds16(src + (size_t)c*8*E_, &As[p][(rb + c*8)*64]);
    };
    auto stageB = [&](int p, int h, int kt) {
        const int rb = h*128 + wave*16;
        const short* src = Bg + (size_t)(rb + sr8)*E_ + kt*64 + scs;
        #pragma unroll
        for (int c=0;c<2;c++)
            gl2lds16(src + (size_t)c*8*E_, &Bs[p][(rb + c*8)*64]);
    };

    short8v a[4][2], b[4][2];
    auto rdA = [&](int p, int row16, int ks) -> short8v {
        return *(const short8v*)&As[p][swz_off(wr*128 + row16*16 + l15, quad + ks*4)];
    };
    auto rdB = [&](int p, int row16, int ks) -> short8v {
        return *(const short8v*)&Bs[p][swz_off(wc*64  + row16*16 + l15, quad + ks*4)];
    };
    auto mm = [&](int mbase, int nbase) {
        #pragma unroll
        for (int mt=0;mt<4;mt++)
            #pragma unroll
            for (int nt=0;nt<2;nt++)
                #pragma unroll
                for (int ks=0;ks<2;ks++)
                    acc[mbase+mt][nbase+nt] = __builtin_amdgcn_mfma_f32_16x16x32_bf16(
                        a[mt][ks], b[nbase+nt][ks], acc[mbase+mt][nbase+nt], 0,0,0);
    };

    auto ktile = [&](int tt, int p) {
        // ---- phase 0 ----
        #pragma unroll
        for (int mt=0;mt<4;mt++){ a[mt][0]=rdA(p,mt,0); a[mt][1]=rdA(p,mt,1); }
        #pragma unroll
        for (int nt=0;nt<2;nt++){ b[nt][0]=rdB(p,nt,0); b[nt][1]=rdB(p,nt,1); }
        if (tt+1 < 16) stageA(p^1, 0, tt+1);
        __builtin_amdgcn_s_barrier();
        __builtin_amdgcn_s_setprio(1);
        mm(0,0);
        __builtin_amdgcn_s_setprio(0);
        __builtin_amdgcn_s_barrier();
        // ---- phase 1 ----
        #pragma unroll
        for (int nt=2;nt<4;nt++){ b[nt][0]=rdB(p,nt,0); b[nt][1]=rdB(p,nt,1); }
        if (tt+1 < 16) stageA(p^1, 1, tt+1);
        __builtin_amdgcn_s_barrier();
        __builtin_amdgcn_s_setprio(1);
        mm(0,2);
        __builtin_amdgcn_s_setprio(0);
        __builtin_amdgcn_s_barrier();
        // ---- phase 2 ----
        #pragma unroll
        for (int mt=0;mt<4;mt++){ a[mt][0]=rdA(p,4+mt,0); a[mt][1]=rdA(p,4+mt,1); }
        if (tt+2 < 16) stageB(p, 0, tt+2);
        __builtin_amdgcn_s_barrier();
        __builtin_amdgcn_s_setprio(1);
        mm(4,0);
        __builtin_amdgcn_s_setprio(0);
        __builtin_amdgcn_s_barrier();
        // ---- phase 3 ----
        if (tt+2 < 16) stageB(p, 1, tt+2);
        __builtin_amdgcn_s_barrier();
        __builtin_amdgcn_s_setprio(1);
        mm(4,2);
        __builtin_amdgcn_s_setprio(0);
        if (tt+2 < 16)      asm volatile("s_waitcnt vmcnt(4)" ::: "memory");
        else if (tt+1 < 16) asm volatile("s_waitcnt vmcnt(0)" ::: "memory");
        __builtin_amdgcn_s_barrier();
    };

    // prologue: tile0 (A0,A1,B0,B1) + tile1 (B0,B1); A(1) is issued in
    // tile0 ph0/ph1 per the steady schedule.
    stageA(0,0,0); stageA(0,1,0); stageB(0,0,0); stageB(0,1,0);
    stageB(1,0,1); stageB(1,1,1);
    asm volatile("s_waitcnt vmcnt(4)" ::: "memory");   // tile0's 8 loads done
    __builtin_amdgcn_s_barrier();

    #pragma unroll 1
    for (int tb = 0; tb < 16; tb += 2) {
        ktile(tb,   0);
        ktile(tb+1, 1);
    }

    // ---- epilogue: bias + scale + z-dependent scatter (unchanged layouts) --
    #pragma unroll
    for (int nt=0;nt<4;nt++) {
        const int nw = (nf0 & 1023) + wc*64 + nt*16 + l15;  // col within this W
        const float bias = bb[nw];
        const int h = nw >> 6, d = nw & 63;
        #pragma unroll
        for (int mt=0;mt<8;mt++) {
            #pragma unroll
            for (int r=0;r<4;r++) {
                const int m = m0 + wr*128 + mt*16 + quad*4 + r;
                const int b2 = m >> 11, s = m & (S_-1);
                const int bh = (b2<<4) + h;
                const float v = (acc[mt][nt][r] + bias) * sc;
                if (z == 0) {
                    out[((size_t)bh*S_ + s)*D_ + d] = f2bf(v);
                } else if (z == 1) {
                    const int ts = s >> 6, kk = s & 63;
                    const int c = kk*8 + ((d>>3) ^ ((kk>>2)&7));
                    out[((size_t)bh*32 + ts)*4096 + c*8 + (d&7)] = f2bf(v);
                } else {
                    const int ts = s >> 6, sk = s & 63;
                    const int c = d*8 + ((sk>>3) ^ (d&7));
                    out[((size_t)bh*32 + ts)*4096 + c*8 + (sk&7)] = f2bf(v);
                }
            }
        }
    }
}

// ---------------------------------------------------------------------------
// Causal flash attention, LDS-staged K/V (unchanged from R8).
// ---------------------------------------------------------------------------
__global__ __launch_bounds__(256, 1) void attn_kernel(
    const short* __restrict__ Q, const short* __restrict__ K, const short* __restrict__ V,
    short* __restrict__ AO)
{
    const int bh = blockIdx.x;
    const int qb = (gridDim.y - 1 - blockIdx.y) * 128;
    const int t = threadIdx.x;
    const int wave = t >> 6, lane = t & 63;
    const int quad = lane >> 4, l15 = lane & 15;

    const short* Qp = Q + (size_t)bh * (S_*D_);
    const short* Kp = K + (size_t)bh * (S_*D_);
    const short* Vp = V + (size_t)bh * (S_*D_);

    __shared__ __align__(16) short KVs[2][8192];          // [parity][K 8KB | V 8KB]
    __shared__ __align__(16) short Psl[2][4][2][16*72];   // [parity][wave][qtile]

    const int qA = qb + wave*16;
    const int qB = qb + 64 + wave*16;
    const short* qa = Qp + (size_t)(qA + l15)*D_ + quad*8;
    const short8v qA0 = *(const short8v*)qa, qA1 = *(const short8v*)(qa + 32);
    const short* qbp = Qp + (size_t)(qB + l15)*D_ + quad*8;
    const short8v qB0 = *(const short8v*)qbp, qB1 = *(const short8v*)(qbp + 32);

    const int qrbA = qA + quad*4;
    const int qrbB = qB + quad*4;

    floatx4 oA[4], oB[4];
    #pragma unroll
    for (int i=0;i<4;i++) { oA[i] = (floatx4){0,0,0,0}; oB[i] = (floatx4){0,0,0,0}; }
    float tsA[4] = {0,0,0,0}, tsB[4] = {0,0,0,0};

    const int L = (qb >> 6) + 2;     // #tiles; even
    const int swz = l15 & 7;

    auto stage = [&](int kt, int p) {
        const short* src = ((wave < 2) ? Kp : Vp) + (size_t)kt*4096 + (wave&1)*2048 + lane*8;
        short* dst = &KVs[p][((wave < 2) ? 0 : 4096) + (wave&1)*2048];
        #pragma unroll
        for (int c=0;c<4;c++)
            gl2lds16(src + c*512, dst + c*512);
    };
    auto qk2 = [&](const short* KL, floatx4 (&sA)[4], floatx4 (&sB)[4]) {
        #pragma unroll
        for (int h=0; h<4; h++) {
            const int rowc = (4*l15 + h)*8;
            short8v b0 = *(const short8v*)(KL + (rowc + (quad       ^ swz))*8);
            short8v b1 = *(const short8v*)(KL + (rowc + ((4 + quad) ^ swz))*8);
            sA[h] = (floatx4){0.f,0.f,0.f,0.f};
            sA[h] = __builtin_amdgcn_mfma_f32_16x16x32_bf16(qA0, b0, sA[h], 0,0,0);
            sA[h] = __builtin_amdgcn_mfma_f32_16x16x32_bf16(qA1, b1, sA[h], 0,0,0);
            sB[h] = (floatx4){0.f,0.f,0.f,0.f};
            sB[h] = __builtin_amdgcn_mfma_f32_16x16x32_bf16(qB0, b0, sB[h], 0,0,0);
            sB[h] = __builtin_amdgcn_mfma_f32_16x16x32_bf16(qB1, b1, sB[h], 0,0,0);
        }
    };
    auto soft_u = [&](floatx4 (&s)[4], float* ts, short* pw, int qrb, int k0) {
        const int kk = k0 + 4*l15;
        #pragma unroll
        for (int r=0; r<4; r++) {
            const int qr = qrb + r;
            float p[4];
            #pragma unroll
            for (int h=0; h<4; h++) {
                const float e = fast_exp2(s[h][r]);
                p[h] = (kk + h > qr) ? 0.f : e;
            }
            ts[r] += (p[0] + p[1]) + (p[2] + p[3]);
            int2 pkv = { (int)pk_bf16(p[0], p[1]), (int)pk_bf16(p[2], p[3]) };
            *(int2*)(pw + (quad*4 + r)*72 + l15*4) = pkv;
        }
    };
    short8v vr[4][2];
    auto loadv = [&](const short* VL) {
        #pragma unroll
        for (int dt=0; dt<4; dt++) {
            const int rowc = (dt*16 + l15)*8;
            vr[dt][0] = *(const short8v*)(VL + (rowc + (quad       ^ swz))*8);
            vr[dt][1] = *(const short8v*)(VL + (rowc + ((4 + quad) ^ swz))*8);
        }
    };
    auto pv = [&](const short* pw, floatx4 (&o)[4]) {
        const short8v pf0 = *(const short8v*)(pw + l15*72 + quad*8);
        const short8v pf1 = *(const short8v*)(pw + l15*72 + 32 + quad*8);
        #pragma unroll
        for (int dt=0; dt<4; dt++) {
            o[dt] = __builtin_amdgcn_mfma_f32_16x16x32_bf16(pf0, vr[dt][0], o[dt], 0,0,0);
            o[dt] = __builtin_amdgcn_mfma_f32_16x16x32_bf16(pf1, vr[dt][1], o[dt], 0,0,0);
        }
    };

    // ---- prologue: tile 0 ----
    stage(0, 0);
    __syncthreads();
    stage(1, 1);
    {
        floatx4 sA[4], sB[4];
        qk2(&KVs[0][0], sA, sB);
        loadv(&KVs[0][4096]);
        soft_u(sA, tsA, &Psl[0][wave][0][0], qrbA, 0);
        soft_u(sB, tsB, &Psl[0][wave][1][0], qrbB, 0);
    }

    for (int kt = 1; kt < L; kt++) {
        const int p = kt & 1;
        __syncthreads();
        if (kt + 1 < L) stage(kt + 1, p ^ 1);
        floatx4 sA[4], sB[4];
        qk2(&KVs[p][0], sA, sB);
        pv(&Psl[p^1][wave][0][0], oA);
        pv(&Psl[p^1][wave][1][0], oB);
        loadv(&KVs[p][4096]);
        const int k0 = kt << 6;
        soft_u(sA, tsA, &Psl[p][wave][0][0], qrbA, k0);
        soft_u(sB, tsB, &Psl[p][wave][1][0], qrbB, k0);
    }

    pv(&Psl[1][wave][0][0], oA);
    pv(&Psl[1][wave][1][0], oB);

    float lA[4], lB[4];
    #pragma unroll
    for (int r=0; r<4; r++) {
        float a = tsA[r], b = tsB[r];
        #pragma unroll
        for (int off=1; off<16; off<<=1) {
            a += __shfl_xor(a, off);
            b += __shfl_xor(b, off);
        }
        lA[r] = a; lB[r] = b;
    }

    const int b = bh >> 4, h = bh & 15;
    #pragma unroll
    for (int dt=0; dt<4; dt++) {
        #pragma unroll
        for (int r=0; r<4; r++) {
            const int d = dt*16 + l15;
            const int sA_ = qA + quad*4 + r;
            const int sB_ = qB + quad*4 + r;
            AO[((size_t)(b*S_ + sA_)*H_ + h)*D_ + d] = f2bf(oA[dt][r] / lA[r]);
            AO[((size_t)(b*S_ + sB_)*H_ + h)*D_ + d] = f2bf(oB[dt][r] / lB[r]);
        }
    }
}

// ---------------------------------------------------------------------------
// Output GEMM: 128m x 64n tiles (512 blocks = 2/CU for barrier overlap),
// BK=64, XOR-swizzled LDS, XCD swizzle m = lin&31.
// Wave w: rows [32w,32w+32) x all 64 n -> acc[2][4].
// ---------------------------------------------------------------------------
__global__ __launch_bounds__(256) void out_gemm(
    const short* __restrict__ A, const short* __restrict__ Wto,
    const float* __restrict__ bo, float* __restrict__ out)
{
    __shared__ __align__(16) short As[128*64];
    __shared__ __align__(16) short Bs[64*64];

    const int t = threadIdx.x;
    const int wave = t >> 6, lane = t & 63;
    const int quad = lane >> 4, l15 = lane & 15;
    const int lin = blockIdx.x;
    const int m0 = (lin & 31) * 128;
    const int n0 = (lin >> 5) * 64;
    const int sr8 = lane >> 3;
    const int scs = ((lane & 7) ^ sr8) * 8;

    floatx4 acc[2][4];
    #pragma unroll
    for (int i=0;i<2;i++)
        #pragma unroll
        for (int j=0;j<4;j++) acc[i][j] = (floatx4){0.f,0.f,0.f,0.f};

    for (int k0 = 0; k0 < E_; k0 += 64) {
        #pragma unroll
        for (int c=0;c<4;c++) {
            const int rb = wave*32 + c*8;
            gl2lds16(A + (size_t)(m0+rb+sr8)*E_ + k0 + scs, &As[rb*64]);
        }
        #pragma unroll
        for (int c=0;c<2;c++) {
            const int rb = wave*16 + c*8;
            gl2lds16(Wto + (size_t)(n0+rb+sr8)*E_ + k0 + scs, &Bs[rb*64]);
        }
        __syncthreads();
        #pragma unroll
        for (int ks=0; ks<2; ks++) {
            const int cg = quad + ks*4;
            short8v a[2], b[4];
            #pragma unroll
            for (int mt=0;mt<2;mt++) a[mt] = *(const short8v*)&As[swz_off(wave*32+mt*16+l15, cg)];
            #pragma unroll
            for (int nt=0;nt<4;nt++) b[nt] = *(const short8v*)&Bs[swz_off(nt*16+l15, cg)];
            #pragma unroll
            for (int mt=0;mt<2;mt++)
                #pragma unroll
                for (int nt=0;nt<4;nt++)
                    acc[mt][nt] = __builtin_amdgcn_mfma_f32_16x16x32_bf16(a[mt], b[nt], acc[mt][nt], 0,0,0);
        }
        __syncthreads();
    }

    #pragma unroll
    for (int nt=0;nt<4;nt++) {
        const int n = n0 + nt*16 + l15;
        const float bias = bo[n];
        #pragma unroll
        for (int mt=0;mt<2;mt++) {
            #pragma unroll
            for (int r=0;r<4;r++) {
                const int m = m0 + wave*32 + mt*16 + quad*4 + r;
                out[(size_t)m*E_ + n] = acc[mt][nt][r] + bias;
            }
        }
    }
}

extern "C" void kernel_launch(void* const* d_in, const int* in_sizes, int n_in,
                              void* d_out, int out_size, void* d_ws, size_t ws_size,
                              hipStream_t stream)
{
    const float* x  = (const float*)d_in[0];
    const float* Wq = (const float*)d_in[1];
    const float* bq = (const float*)d_in[2];
    const float* Wk = (const float*)d_in[3];
    const float* bk = (const float*)d_in[4];
    const float* Wv = (const float*)d_in[5];
    const float* bv = (const float*)d_in[6];
    const float* Wo = (const float*)d_in[7];
    const float* bo = (const float*)d_in[8];

    short* xb  = (short*)d_ws;                   // bf16 [4096,1024]
    short* Tq  = xb  + (size_t)M_ * E_;          // bf16 Wq^T [n][k]; Tq|Tk|Tv fused
    short* Tk  = Tq  + (size_t)E_ * E_;
    short* Tv  = Tk  + (size_t)E_ * E_;
    short* To  = Tv  + (size_t)E_ * E_;
    short* Qw  = To  + (size_t)E_ * E_;          // bf16 [B,H,S,D] (exp2-scaled)
    short* Kw  = Qw  + (size_t)M_ * E_;          // bf16 tiled-swizzled K
    short* Vw  = Kw  + (size_t)M_ * E_;          // bf16 tiled-swizzled V
    short* AOw = Vw  + (size_t)M_ * E_;          // bf16 [B,S,H,D]

    dim3 blk(256);
    convert_x<<<dim3((M_*E_)/(256*8)), blk, 0, stream>>>(x, xb);
    transpose_w<<<dim3(E_/32, E_/32, 4), blk, 0, stream>>>(Wq, Wk, Wv, Wo, Tq, Tk, Tv, To);
    qkv_gemm<<<dim3(192), dim3(512), 0, stream>>>(xb, Tq, bq, bk, bv, Qw, Kw, Vw);
    attn_kernel<<<dim3(B_*H_, S_/128), blk, 0, stream>>>(Qw, Kw, Vw, AOw);
    out_gemm<<<dim3(512), blk, 0, stream>>>(AOw, To, bo, (float*)d_out);
}

// Round 3
// 184.216 us; speedup vs baseline: 1.0682x; 1.0611x over previous
//
#include <hip/hip_runtime.h>
#include <hip/hip_bf16.h>
#include <math.h>

#define B_ 2
#define S_ 2048
#define E_ 1024
#define H_ 16
#define D_ 64
#define M_ (B_*S_)

typedef __attribute__((ext_vector_type(8))) short short8v;
typedef __attribute__((ext_vector_type(4))) float floatx4;

__device__ __forceinline__ short f2bf(float f) {
    union { float f; unsigned u; } x; x.f = f;
    unsigned r = (x.u + 0x7fffu + ((x.u >> 16) & 1u)) >> 16;  // RNE
    return (short)r;
}

// pack two fp32 -> two bf16 in one v_perm_b32 (round-half-up)
__device__ __forceinline__ unsigned pk_bf16(float a, float b) {
    union { float f; unsigned u; } x, y;
    x.f = a; y.f = b;
    return __builtin_amdgcn_perm(y.u + 0x8000u, x.u + 0x8000u, 0x07060302u);
}

__device__ __forceinline__ float fast_exp2(float x) {
#if __has_builtin(__builtin_amdgcn_exp2f)
    return __builtin_amdgcn_exp2f(x);
#else
    return __expf(x * 0.6931471805599453f);
#endif
}

// async global->LDS, 16B per lane; LDS dest = wave-uniform base + lane*16
__device__ __forceinline__ void gl2lds16(const void* g, void* l) {
    __builtin_amdgcn_global_load_lds(
        (const __attribute__((address_space(1))) void*)g,
        (__attribute__((address_space(3))) void*)l, 16, 0, 0);
}

// XOR-swizzled fragment offset into a 64-col bf16 LDS tile:
// logical (row, 16B-chunk cg) lives at row*64 + ((cg ^ (row&7))*8).
__device__ __forceinline__ int swz_off(int row, int cg) {
    return row*64 + (((cg ^ (row & 7)) & 7) << 3);
}

// ---------------------------------------------------------------------------
// Pre-pass (merged): bid<2048 -> x fp32->bf16 flat copy;
// bid>=2048 -> W [k][n] fp32 -> Wt [n][k] bf16 (32x32 LDS tile transpose).
// ---------------------------------------------------------------------------
__global__ __launch_bounds__(256) void prep(
    const float* __restrict__ x, short* __restrict__ xb,
    const float* __restrict__ W0, const float* __restrict__ W1,
    const float* __restrict__ W2, const float* __restrict__ W3,
    short* __restrict__ T0, short* __restrict__ T1,
    short* __restrict__ T2, short* __restrict__ T3)
{
    const int bid = blockIdx.x;
    if (bid < 2048) {
        const size_t i = ((size_t)bid*256 + threadIdx.x) * 8;
        float4 a = *(const float4*)(x + i);
        float4 b = *(const float4*)(x + i + 4);
        int4 p = { (int)pk_bf16(a.x,a.y), (int)pk_bf16(a.z,a.w),
                   (int)pk_bf16(b.x,b.y), (int)pk_bf16(b.z,b.w) };
        *(int4*)(xb + i) = p;
        return;
    }
    const int tb = bid - 2048;
    const int z = tb >> 10;
    const float* W = (z==0)?W0:(z==1)?W1:(z==2)?W2:W3;
    short*       T = (z==0)?T0:(z==1)?T1:(z==2)?T2:T3;
    __shared__ float tile[32][33];
    const int k0 = ((tb>>5)&31)*32, n0 = (tb&31)*32;
    const int r = threadIdx.x >> 5, c = threadIdx.x & 31;
    #pragma unroll
    for (int i=0;i<4;i++)
        tile[r+8*i][c] = W[(size_t)(k0+r+8*i)*E_ + n0 + c];
    __syncthreads();
    #pragma unroll
    for (int i=0;i<4;i++)
        T[(size_t)(n0+r+8*i)*E_ + k0 + c] = f2bf(tile[c][r+8*i]);
}

// ---------------------------------------------------------------------------
// Fused QKV GEMM — 256x256 tile, BK=64, 8 waves (2Mx4N), 512 threads,
// 8-phase counted-vmcnt schedule (T3+T4) + setprio (T5) + XOR swizzle (T2).
// Grid 192 = 16m x 12n (all tiles the problem has), XCD-chunked swizzle.
// LDS: one 128 KiB SMEM block, main loop uses [A dbuf | B dbuf]; the
// epilogue reuses it as 8 x 16 KiB per-wave transpose scratch so all three
// z output layouts are written with coalesced 16B stores (was 128 scalar
// 2B scattered stores/thread -> WRITE_SIZE bloat 37.9MB).
//
// Per K-tile (4 phases, 16 MFMA each):
//   ph0: ds_read a[M0-3], b[N0-1]; stage A-half0(t+1) -> buf^1 ; MFMA M0-3xN0-1
//   ph1: ds_read b[N2-3];          stage A-half1(t+1) -> buf^1 ; MFMA M0-3xN2-3
//   ph2: ds_read a[M4-7];          stage B-half0(t+2) -> buf   ; MFMA M4-7xN0-1
//   ph3:                           stage B-half1(t+2) -> buf   ; MFMA M4-7xN2-3
//        then s_waitcnt vmcnt(4) + raw s_barrier. Never vmcnt(0) mid-loop.
// ---------------------------------------------------------------------------
__global__ __launch_bounds__(512, 2) void qkv_gemm(
    const short* __restrict__ xb, const short* __restrict__ Wt,
    const float* __restrict__ bq, const float* __restrict__ bk, const float* __restrict__ bv,
    short* __restrict__ Qo, short* __restrict__ Ko, short* __restrict__ Vo)
{
    __shared__ __align__(16) short SMEM[65536];      // 128 KiB
    short* Asp = SMEM;                                // [2][16384]
    short* Bsp = SMEM + 32768;                        // [2][16384]

    const int t = threadIdx.x;
    const int wave = t >> 6, lane = t & 63;
    const int quad = lane >> 4, l15 = lane & 15;
    const int wr = wave >> 2, wc = wave & 3;          // 2x4 wave grid

    const int bid = blockIdx.x;
    const int sw  = (bid & 7) * 24 + (bid >> 3);      // XCD chunk (192%8==0)
    const int m0  = (sw / 12) * 256;                  // 16 m-tiles
    const int nti = sw % 12;                          // 12 n-tiles
    const int nf0 = nti * 256;
    const int z   = nf0 >> 10;
    const float* bb = (z==0) ? bq : (z==1) ? bk : bv;
    short* out      = (z==0) ? Qo : (z==1) ? Ko : Vo;
    const float sc  = (z==0) ? 0.18033688011112042f : 1.0f;

    const int sr8 = lane >> 3;
    const int scs = ((lane & 7) ^ sr8) * 8;           // pre-swizzled src chunk

    const short* Ag = xb + (size_t)m0  * E_;
    const short* Bg = Wt + (size_t)nf0 * E_;

    floatx4 acc[8][4];
    #pragma unroll
    for (int i=0;i<8;i++)
        #pragma unroll
        for (int j=0;j<4;j++) acc[i][j] = (floatx4){0.f,0.f,0.f,0.f};

    auto stageA = [&](int p, int h, int kt) {
        const int rb = h*128 + wave*16;
        const short* src = Ag + (size_t)(rb + sr8)*E_ + kt*64 + scs;
        #pragma unroll
        for (int c=0;c<2;c++)
            gl2lds16(src + (size_t)c*8*E_, Asp + p*16384 + (rb + c*8)*64);
    };
    auto stageB = [&](int p, int h, int kt) {
        const int rb = h*128 + wave*16;
        const short* src = Bg + (size_t)(rb + sr8)*E_ + kt*64 + scs;
        #pragma unroll
        for (int c=0;c<2;c++)
            gl2lds16(src + (size_t)c*8*E_, Bsp + p*16384 + (rb + c*8)*64);
    };

    short8v a[4][2], b[4][2];
    auto rdA = [&](int p, int row16, int ks) -> short8v {
        return *(const short8v*)&Asp[p*16384 + swz_off(wr*128 + row16*16 + l15, quad + ks*4)];
    };
    auto rdB = [&](int p, int row16, int ks) -> short8v {
        return *(const short8v*)&Bsp[p*16384 + swz_off(wc*64  + row16*16 + l15, quad + ks*4)];
    };
    auto mm = [&](int mbase, int nbase) {
        #pragma unroll
        for (int mt=0;mt<4;mt++)
            #pragma unroll
            for (int nt=0;nt<2;nt++)
                #pragma unroll
                for (int ks=0;ks<2;ks++)
                    acc[mbase+mt][nbase+nt] = __builtin_amdgcn_mfma_f32_16x16x32_bf16(
                        a[mt][ks], b[nbase+nt][ks], acc[mbase+mt][nbase+nt], 0,0,0);
    };

    auto ktile = [&](int tt, int p) {
        // ---- phase 0 ----
        #pragma unroll
        for (int nt=0;nt<2;nt++){ b[nt][0]=rdB(p,nt,0); b[nt][1]=rdB(p,nt,1); }
        #pragma unroll
        for (int mt=0;mt<4;mt++){ a[mt][0]=rdA(p,mt,0); a[mt][1]=rdA(p,mt,1); }
        if (tt+1 < 16) stageA(p^1, 0, tt+1);
        __builtin_amdgcn_s_barrier();
        __builtin_amdgcn_s_setprio(1);
        mm(0,0);
        __builtin_amdgcn_s_setprio(0);
        __builtin_amdgcn_s_barrier();
        // ---- phase 1 ----
        #pragma unroll
        for (int nt=2;nt<4;nt++){ b[nt][0]=rdB(p,nt,0); b[nt][1]=rdB(p,nt,1); }
        if (tt+1 < 16) stageA(p^1, 1, tt+1);
        __builtin_amdgcn_s_barrier();
        __builtin_amdgcn_s_setprio(1);
        mm(0,2);
        __builtin_amdgcn_s_setprio(0);
        __builtin_amdgcn_s_barrier();
        // ---- phase 2 ----
        #pragma unroll
        for (int mt=0;mt<4;mt++){ a[mt][0]=rdA(p,4+mt,0); a[mt][1]=rdA(p,4+mt,1); }
        if (tt+2 < 16) stageB(p, 0, tt+2);
        __builtin_amdgcn_s_barrier();
        __builtin_amdgcn_s_setprio(1);
        mm(4,0);
        __builtin_amdgcn_s_setprio(0);
        __builtin_amdgcn_s_barrier();
        // ---- phase 3 ----
        if (tt+2 < 16) stageB(p, 1, tt+2);
        __builtin_amdgcn_s_barrier();
        __builtin_amdgcn_s_setprio(1);
        mm(4,2);
        __builtin_amdgcn_s_setprio(0);
        if (tt+2 < 16)      asm volatile("s_waitcnt vmcnt(4)" ::: "memory");
        else if (tt+1 < 16) asm volatile("s_waitcnt vmcnt(0)" ::: "memory");
        __builtin_amdgcn_s_barrier();
    };

    // prologue: tile0 (A0,A1,B0,B1) + tile1 (B0,B1)
    stageA(0,0,0); stageA(0,1,0); stageB(0,0,0); stageB(0,1,0);
    stageB(1,0,1); stageB(1,1,1);
    asm volatile("s_waitcnt vmcnt(4)" ::: "memory");   // tile0's 8 loads done
    __builtin_amdgcn_s_barrier();

    #pragma unroll 1
    for (int tb = 0; tb < 16; tb += 2) {
        ktile(tb,   0);
        ktile(tb+1, 1);
    }

    // ---- epilogue: per-wave LDS transpose -> coalesced 16B stores ---------
    // After the last ktile barrier all main-loop LDS reads are complete.
    short* wbuf = SMEM + wave*8192;                   // 16 KiB per wave
    const int nwbase = (nf0 & 1023) + wc*64;          // multiple of 64
    const int h = nwbase >> 6;                        // head, fixed per wave
    const int mbase = m0 + wr*128;                    // 128-row strip (one b2)
    const int bh = ((mbase >> 11) << 4) + h;

    if (z != 2) {
        // row-major [r=128][c=64] bf16, chunk-swizzled like swz_off
        #pragma unroll
        for (int nt=0;nt<4;nt++) {
            const int c = nt*16 + l15;
            const float bias = bb[nwbase + c];
            #pragma unroll
            for (int mt=0;mt<8;mt++)
                #pragma unroll
                for (int r=0;r<4;r++) {
                    const int rr = mt*16 + quad*4 + r;
                    wbuf[rr*64 + (((c>>3) ^ (rr&7)) << 3) + (c&7)] =
                        f2bf((acc[mt][nt][r] + bias) * sc);
                }
        }
        asm volatile("s_waitcnt lgkmcnt(0)" ::: "memory");
        __builtin_amdgcn_sched_barrier(0);
        #pragma unroll
        for (int it=0; it<16; it++) {
            const int rr = it*8 + (lane>>3);
            const int cg = lane & 7;
            short8v v = *(const short8v*)&wbuf[rr*64 + ((cg ^ (rr&7)) << 3)];
            const int s = (mbase + rr) & (S_-1);
            if (z == 0) {
                *(short8v*)&out[((size_t)bh*S_ + s)*D_ + cg*8] = v;
            } else {  // z == 1: K tiles, 16B run along d&7
                const int ts = s >> 6, kk = s & 63;
                const int csw = kk*8 + (cg ^ ((kk>>2)&7));
                *(short8v*)&out[((size_t)bh*32 + ts)*4096 + csw*8] = v;
            }
        }
    } else {
        // V: contiguous axis is s -> transposed scratch [d=64][s=128],
        // chunk cg = s>>3 (16/row), swizzle cg ^= (d&15)
        #pragma unroll
        for (int nt=0;nt<4;nt++) {
            const int d = nt*16 + l15;
            const float bias = bb[nwbase + d];
            #pragma unroll
            for (int mt=0;mt<8;mt++)
                #pragma unroll
                for (int r=0;r<4;r++) {
                    const int sl = mt*16 + quad*4 + r;
                    wbuf[d*128 + (((sl>>3) ^ (d&15)) << 3) + (sl&7)] =
                        f2bf(acc[mt][nt][r] + bias);
                }
        }
        asm volatile("s_waitcnt lgkmcnt(0)" ::: "memory");
        __builtin_amdgcn_sched_barrier(0);
        #pragma unroll
        for (int it=0; it<16; it++) {
            const int d  = (it&7)*8 + (lane>>3);
            const int cg = (it>>3)*8 + (lane&7);     // s-chunk 0..15
            short8v v = *(const short8v*)&wbuf[d*128 + ((cg ^ (d&15)) << 3)];
            const int sb = (mbase & (S_-1)) + cg*8;  // first s of the run
            const int ts = sb >> 6;
            const int csw = d*8 + (((sb>>3)&7) ^ (d&7));
            *(short8v*)&out[((size_t)bh*32 + ts)*4096 + csw*8] = v;
        }
    }
}

// ---------------------------------------------------------------------------
// Causal flash attention, LDS-staged K/V (+ T5 setprio around MFMA clusters).
// ---------------------------------------------------------------------------
__global__ __launch_bounds__(256, 1) void attn_kernel(
    const short* __restrict__ Q, const short* __restrict__ K, const short* __restrict__ V,
    short* __restrict__ AO)
{
    const int bh = blockIdx.x;
    const int qb = (gridDim.y - 1 - blockIdx.y) * 128;
    const int t = threadIdx.x;
    const int wave = t >> 6, lane = t & 63;
    const int quad = lane >> 4, l15 = lane & 15;

    const short* Qp = Q + (size_t)bh * (S_*D_);
    const short* Kp = K + (size_t)bh * (S_*D_);
    const short* Vp = V + (size_t)bh * (S_*D_);

    __shared__ __align__(16) short KVs[2][8192];          // [parity][K 8KB | V 8KB]
    __shared__ __align__(16) short Psl[2][4][2][16*72];   // [parity][wave][qtile]

    const int qA = qb + wave*16;
    const int qB = qb + 64 + wave*16;
    const short* qa = Qp + (size_t)(qA + l15)*D_ + quad*8;
    const short8v qA0 = *(const short8v*)qa, qA1 = *(const short8v*)(qa + 32);
    const short* qbp = Qp + (size_t)(qB + l15)*D_ + quad*8;
    const short8v qB0 = *(const short8v*)qbp, qB1 = *(const short8v*)(qbp + 32);

    const int qrbA = qA + quad*4;
    const int qrbB = qB + quad*4;

    floatx4 oA[4], oB[4];
    #pragma unroll
    for (int i=0;i<4;i++) { oA[i] = (floatx4){0,0,0,0}; oB[i] = (floatx4){0,0,0,0}; }
    float tsA[4] = {0,0,0,0}, tsB[4] = {0,0,0,0};

    const int L = (qb >> 6) + 2;     // #tiles; even
    const int swz = l15 & 7;

    auto stage = [&](int kt, int p) {
        const short* src = ((wave < 2) ? Kp : Vp) + (size_t)kt*4096 + (wave&1)*2048 + lane*8;
        short* dst = &KVs[p][((wave < 2) ? 0 : 4096) + (wave&1)*2048];
        #pragma unroll
        for (int c=0;c<4;c++)
            gl2lds16(src + c*512, dst + c*512);
    };
    auto qk2 = [&](const short* KL, floatx4 (&sA)[4], floatx4 (&sB)[4]) {
        __builtin_amdgcn_s_setprio(1);
        #pragma unroll
        for (int h=0; h<4; h++) {
            const int rowc = (4*l15 + h)*8;
            short8v b0 = *(const short8v*)(KL + (rowc + (quad       ^ swz))*8);
            short8v b1 = *(const short8v*)(KL + (rowc + ((4 + quad) ^ swz))*8);
            sA[h] = (floatx4){0.f,0.f,0.f,0.f};
            sA[h] = __builtin_amdgcn_mfma_f32_16x16x32_bf16(qA0, b0, sA[h], 0,0,0);
            sA[h] = __builtin_amdgcn_mfma_f32_16x16x32_bf16(qA1, b1, sA[h], 0,0,0);
            sB[h] = (floatx4){0.f,0.f,0.f,0.f};
            sB[h] = __builtin_amdgcn_mfma_f32_16x16x32_bf16(qB0, b0, sB[h], 0,0,0);
            sB[h] = __builtin_amdgcn_mfma_f32_16x16x32_bf16(qB1, b1, sB[h], 0,0,0);
        }
        __builtin_amdgcn_s_setprio(0);
    };
    auto soft_u = [&](floatx4 (&s)[4], float* ts, short* pw, int qrb, int k0) {
        const int kk = k0 + 4*l15;
        #pragma unroll
        for (int r=0; r<4; r++) {
            const int qr = qrb + r;
            float p[4];
            #pragma unroll
            for (int h=0; h<4; h++) {
                const float e = fast_exp2(s[h][r]);
                p[h] = (kk + h > qr) ? 0.f : e;
            }
            ts[r] += (p[0] + p[1]) + (p[2] + p[3]);
            int2 pkv = { (int)pk_bf16(p[0], p[1]), (int)pk_bf16(p[2], p[3]) };
            *(int2*)(pw + (quad*4 + r)*72 + l15*4) = pkv;
        }
    };
    short8v vr[4][2];
    auto loadv = [&](const short* VL) {
        #pragma unroll
        for (int dt=0; dt<4; dt++) {
            const int rowc = (dt*16 + l15)*8;
            vr[dt][0] = *(const short8v*)(VL + (rowc + (quad       ^ swz))*8);
            vr[dt][1] = *(const short8v*)(VL + (rowc + ((4 + quad) ^ swz))*8);
        }
    };
    auto pv = [&](const short* pw, floatx4 (&o)[4]) {
        const short8v pf0 = *(const short8v*)(pw + l15*72 + quad*8);
        const short8v pf1 = *(const short8v*)(pw + l15*72 + 32 + quad*8);
        __builtin_amdgcn_s_setprio(1);
        #pragma unroll
        for (int dt=0; dt<4; dt++) {
            o[dt] = __builtin_amdgcn_mfma_f32_16x16x32_bf16(pf0, vr[dt][0], o[dt], 0,0,0);
            o[dt] = __builtin_amdgcn_mfma_f32_16x16x32_bf16(pf1, vr[dt][1], o[dt], 0,0,0);
        }
        __builtin_amdgcn_s_setprio(0);
    };

    // ---- prologue: tile 0 ----
    stage(0, 0);
    __syncthreads();
    stage(1, 1);
    {
        floatx4 sA[4], sB[4];
        qk2(&KVs[0][0], sA, sB);
        loadv(&KVs[0][4096]);
        soft_u(sA, tsA, &Psl[0][wave][0][0], qrbA, 0);
        soft_u(sB, tsB, &Psl[0][wave][1][0], qrbB, 0);
    }

    for (int kt = 1; kt < L; kt++) {
        const int p = kt & 1;
        __syncthreads();
        if (kt + 1 < L) stage(kt + 1, p ^ 1);
        floatx4 sA[4], sB[4];
        qk2(&KVs[p][0], sA, sB);
        pv(&Psl[p^1][wave][0][0], oA);
        pv(&Psl[p^1][wave][1][0], oB);
        loadv(&KVs[p][4096]);
        const int k0 = kt << 6;
        soft_u(sA, tsA, &Psl[p][wave][0][0], qrbA, k0);
        soft_u(sB, tsB, &Psl[p][wave][1][0], qrbB, k0);
    }

    pv(&Psl[1][wave][0][0], oA);
    pv(&Psl[1][wave][1][0], oB);

    float lA[4], lB[4];
    #pragma unroll
    for (int r=0; r<4; r++) {
        float a = tsA[r], b = tsB[r];
        #pragma unroll
        for (int off=1; off<16; off<<=1) {
            a += __shfl_xor(a, off);
            b += __shfl_xor(b, off);
        }
        lA[r] = a; lB[r] = b;
    }

    const int b = bh >> 4, h = bh & 15;
    #pragma unroll
    for (int dt=0; dt<4; dt++) {
        #pragma unroll
        for (int r=0; r<4; r++) {
            const int d = dt*16 + l15;
            const int sA_ = qA + quad*4 + r;
            const int sB_ = qB + quad*4 + r;
            AO[((size_t)(b*S_ + sA_)*H_ + h)*D_ + d] = f2bf(oA[dt][r] / lA[r]);
            AO[((size_t)(b*S_ + sB_)*H_ + h)*D_ + d] = f2bf(oB[dt][r] / lB[r]);
        }
    }
}

// ---------------------------------------------------------------------------
// Output GEMM: 128m x 64n tiles (512 blocks = 2/CU for barrier overlap),
// BK=64, XOR-swizzled LDS, XCD swizzle m = lin&31.
// ---------------------------------------------------------------------------
__global__ __launch_bounds__(256) void out_gemm(
    const short* __restrict__ A, const short* __restrict__ Wto,
    const float* __restrict__ bo, float* __restrict__ out)
{
    __shared__ __align__(16) short As[128*64];
    __shared__ __align__(16) short Bs[64*64];

    const int t = threadIdx.x;
    const int wave = t >> 6, lane = t & 63;
    const int quad = lane >> 4, l15 = lane & 15;
    const int lin = blockIdx.x;
    const int m0 = (lin & 31) * 128;
    const int n0 = (lin >> 5) * 64;
    const int sr8 = lane >> 3;
    const int scs = ((lane & 7) ^ sr8) * 8;

    floatx4 acc[2][4];
    #pragma unroll
    for (int i=0;i<2;i++)
        #pragma unroll
        for (int j=0;j<4;j++) acc[i][j] = (floatx4){0.f,0.f,0.f,0.f};

    for (int k0 = 0; k0 < E_; k0 += 64) {
        #pragma unroll
        for (int c=0;c<4;c++) {
            const int rb = wave*32 + c*8;
            gl2lds16(A + (size_t)(m0+rb+sr8)*E_ + k0 + scs, &As[rb*64]);
        }
        #pragma unroll
        for (int c=0;c<2;c++) {
            const int rb = wave*16 + c*8;
            gl2lds16(Wto + (size_t)(n0+rb+sr8)*E_ + k0 + scs, &Bs[rb*64]);
        }
        __syncthreads();
        #pragma unroll
        for (int ks=0; ks<2; ks++) {
            const int cg = quad + ks*4;
            short8v a[2], b[4];
            #pragma unroll
            for (int mt=0;mt<2;mt++) a[mt] = *(const short8v*)&As[swz_off(wave*32+mt*16+l15, cg)];
            #pragma unroll
            for (int nt=0;nt<4;nt++) b[nt] = *(const short8v*)&Bs[swz_off(nt*16+l15, cg)];
            #pragma unroll
            for (int mt=0;mt<2;mt++)
                #pragma unroll
                for (int nt=0;nt<4;nt++)
                    acc[mt][nt] = __builtin_amdgcn_mfma_f32_16x16x32_bf16(a[mt], b[nt], acc[mt][nt], 0,0,0);
        }
        __syncthreads();
    }

    #pragma unroll
    for (int nt=0;nt<4;nt++) {
        const int n = n0 + nt*16 + l15;
        const float bias = bo[n];
        #pragma unroll
        for (int mt=0;mt<2;mt++) {
            #pragma unroll
            for (int r=0;r<4;r++) {
                const int m = m0 + wave*32 + mt*16 + quad*4 + r;
                out[(size_t)m*E_ + n] = acc[mt][nt][r] + bias;
            }
        }
    }
}

extern "C" void kernel_launch(void* const* d_in, const int* in_sizes, int n_in,
                              void* d_out, int out_size, void* d_ws, size_t ws_size,
                              hipStream_t stream)
{
    const float* x  = (const float*)d_in[0];
    const float* Wq = (const float*)d_in[1];
    const float* bq = (const float*)d_in[2];
    const float* Wk = (const float*)d_in[3];
    const float* bk = (const float*)d_in[4];
    const float* Wv = (const float*)d_in[5];
    const float* bv = (const float*)d_in[6];
    const float* Wo = (const float*)d_in[7];
    const float* bo = (const float*)d_in[8];

    short* xb  = (short*)d_ws;                   // bf16 [4096,1024]
    short* Tq  = xb  + (size_t)M_ * E_;          // bf16 Wq^T [n][k]; Tq|Tk|Tv fused
    short* Tk  = Tq  + (size_t)E_ * E_;
    short* Tv  = Tk  + (size_t)E_ * E_;
    short* To  = Tv  + (size_t)E_ * E_;
    short* Qw  = To  + (size_t)E_ * E_;          // bf16 [B,H,S,D] (exp2-scaled)
    short* Kw  = Qw  + (size_t)M_ * E_;          // bf16 tiled-swizzled K
    short* Vw  = Kw  + (size_t)M_ * E_;          // bf16 tiled-swizzled V
    short* AOw = Vw  + (size_t)M_ * E_;          // bf16 [B,S,H,D]

    dim3 blk(256);
    prep<<<dim3(2048 + 4096), blk, 0, stream>>>(x, xb, Wq, Wk, Wv, Wo, Tq, Tk, Tv, To);
    qkv_gemm<<<dim3(192), dim3(512), 0, stream>>>(xb, Tq, bq, bk, bv, Qw, Kw, Vw);
    attn_kernel<<<dim3(B_*H_, S_/128), blk, 0, stream>>>(Qw, Kw, Vw, AOw);
    out_gemm<<<dim3(512), blk, 0, stream>>>(AOw, To, bo, (float*)d_out);
}